// Round 5
// baseline (1040.550 us; speedup 1.0000x reference)
//
#include <hip/hip_runtime.h>
#include <math.h>

// ---------------------------------------------------------------------------
// VQ-VAE forward, B=4096. Scalar f32 loss in d_out[0].
//
// ws float layout:
//   wt2g @ 0      : 18432  conv2 W   [(ci*9+tap)*64 + co]
//   Tg   @ 18432  : 33280  convT1 table [code(65)][kh*4+kw][co(32)], row64=0
//   wtd2g@ 51712  : 1536   convT2 W  [(ci*16+tap)*3 + co]
//   w1tg @ 53248  : 864    conv1 W   [(ci*9+tap)*32 + co]
//   normg@ 54112  : 64     ||emb_k||^2
//   tokens @ byte 217088   : 4096*64 uchar
// ---------------------------------------------------------------------------

__global__ __launch_bounds__(256) void k_init(
    const float* __restrict__ w1, const float* __restrict__ w2,
    const float* __restrict__ wd2, float* __restrict__ ws,
    float* __restrict__ out)
{
  int gid = blockIdx.x * 256 + threadIdx.x;
  if (gid == 0) out[0] = 0.f;
  if (gid < 18432) {                       // w2: (64co,32ci,3,3) -> [(ci*9+tap)*64+co]
    int co = gid / 288, j = gid - co*288;
    ws[j*64 + co] = w2[gid];
  }
  if (gid < 1536) {                        // wd2: (32ci,3co,4,4) -> [(ci*16+tap)*3+co]
    int ci = gid / 48, r = gid - ci*48, co = r >> 4, k = r & 15;
    ws[51712 + (ci*16 + k)*3 + co] = wd2[gid];
  }
  if (gid < 864) {                         // w1: (32co,3ci,3,3) -> [(ci*9+tap)*32+co]
    int co = gid / 27, j = gid - co*27;
    ws[53248 + j*32 + co] = w1[gid];
  }
}

// ---------------------------------------------------------------------------
// k_tab: T[code][tap][co] = sum_ci emb[code][ci] * wd1[ci][co][tap]. Row 64 = 0.
// Block 64 also writes ||emb_k||^2. grid 65 x 512.
// ---------------------------------------------------------------------------
__global__ __launch_bounds__(512) void k_tab(
    const float* __restrict__ emb, const float* __restrict__ wd1,
    float* __restrict__ ws)
{
  float* Tg = ws + 18432;
  const int code = blockIdx.x;
  const int tid = threadIdx.x;
  if (code == 64) {
    Tg[64*512 + tid] = 0.f;
    if (tid < 64) {
      const float* e = emb + tid*64;
      float s = 0.f;
      for (int j = 0; j < 64; j++) s += e[j]*e[j];
      ws[54112 + tid] = s;
    }
    return;
  }
  __shared__ float wsh[4096];
  float acc = 0.f;
  for (int cc = 0; cc < 8; cc++) {
    for (int i = tid; i < 4096; i += 512) wsh[i] = wd1[cc*4096 + i];
    __syncthreads();
    const float* eb = emb + code*64 + cc*8;
#pragma unroll
    for (int cil = 0; cil < 8; cil++) acc += eb[cil] * wsh[cil*512 + tid];
    __syncthreads();
  }
  Tg[code*512 + (tid & 15)*32 + (tid >> 4)] = acc;
}

// ---------------------------------------------------------------------------
// k123: half-image per block (grid 8192). conv1 -> conv2 -> VQ, all weights
// LDS-staged (conv2 in 8-ci chunks), h1 padded to stride-12 rows with
// half-independent column origin so conv2 reads are aligned b128+b32.
// ---------------------------------------------------------------------------
__global__ __launch_bounds__(256) void k123(
    const float* __restrict__ x,
    const float* __restrict__ b1v, const float* __restrict__ b2v,
    const float* __restrict__ emb,
    const float* __restrict__ ws,
    unsigned char* __restrict__ tokens,
    float* __restrict__ loss)
{
  __shared__ __align__(16) float smem[14320];
  float* h1   = smem;            // [32][17][12] = 6528, row0/col-borders zero
  float* xt   = smem + 6528;     // 2248 (2142 used); xe alias after conv1
  float* xe   = smem + 6528;     // [32][68] swizzled x_enc
  float* w1s  = smem + 8776;     // 864 conv1 weights
  float* w2s  = smem + 9640;     // 4608 conv2 chunk buffer; enat alias after
  float* enat = smem + 9640;     // [64][68]
  float* norms= smem + 14248;    // 64
  float* red  = smem + 14312;    // 8

  const int tid  = threadIdx.x;
  const int half = blockIdx.x & 1;
  const int b    = blockIdx.x >> 1;
  const float* wt2g = ws;

  // ---- phase 0: zero h1; stage xt (value-or-zero), w1s, norms ----
  {
    float4* h4 = (float4*)h1;
    float4 z = make_float4(0.f, 0.f, 0.f, 0.f);
    for (int i = tid; i < 1632; i += 256) h4[i] = z;
    const int ixbase = 14*half - 1;
    const float* xb = x + b*3072;
    for (int idx = tid; idx < 2142; idx += 256) {
      int ci = idx / 714;
      int rem = idx - ci*714;
      int r = rem / 21, cc = rem - r*21;
      int xr = r - 1, xc = ixbase + cc;
      float v = 0.f;
      if (cc < 19 && (unsigned)xr < 32u && (unsigned)xc < 32u)
        v = xb[ci*1024 + xr*32 + xc];
      xt[idx] = v;
    }
    float4* d4 = (float4*)w1s;
    const float4* s4g = (const float4*)(ws + 53248);
    if (tid < 216) d4[tid] = s4g[tid];
    if (tid < 64) norms[tid] = ws[54112 + tid];
  }
  __syncthreads();

  // ---- phase 1: conv1 (3->32, k3 s2 p1) + ReLU -> h1 interior ----
  // stored col = lc + 1 - half  (so conv2 read base is always 4*wp, aligned)
  {
    const int cs = tid >> 6, l = tid & 63;
    float acc[3][8];
#pragma unroll
    for (int i = 0; i < 3; i++)
#pragma unroll
      for (int q = 0; q < 8; q++) acc[i][q] = 0.f;
#pragma unroll
    for (int ci = 0; ci < 3; ci++)
#pragma unroll
      for (int kh = 0; kh < 3; kh++)
#pragma unroll
        for (int kw = 0; kw < 3; kw++) {
          const float* wp = &w1s[(ci*9 + kh*3 + kw)*32 + cs*8];
          const float4 w0 = *(const float4*)wp;
          const float4 w1_ = *(const float4*)(wp + 4);
#pragma unroll
          for (int i = 0; i < 3; i++) {
            int sp = i*64 + l; int spc = sp < 144 ? sp : 143;
            int lc = spc >> 4, oh1 = spc & 15;
            float xv = xt[ci*714 + (2*oh1 + kh)*21 + (2*lc + kw)];
            acc[i][0] += w0.x*xv; acc[i][1] += w0.y*xv; acc[i][2] += w0.z*xv; acc[i][3] += w0.w*xv;
            acc[i][4] += w1_.x*xv; acc[i][5] += w1_.y*xv; acc[i][6] += w1_.z*xv; acc[i][7] += w1_.w*xv;
          }
        }
    const float4 b0 = *(const float4*)&b1v[cs*8];
    const float4 b1_ = *(const float4*)&b1v[cs*8 + 4];
    float bias[8] = {b0.x,b0.y,b0.z,b0.w,b1_.x,b1_.y,b1_.z,b1_.w};
#pragma unroll
    for (int i = 0; i < 3; i++) {
      int sp = i*64 + l;
      if (sp < 144) {
        int lc = sp >> 4, oh1 = sp & 15;
#pragma unroll
        for (int q = 0; q < 8; q++) {
          float v = acc[i][q] + bias[q];
          h1[(cs*8 + q)*204 + (oh1 + 1)*12 + (lc + 1 - half)] = v > 0.f ? v : 0.f;
        }
      }
    }
  }
  __syncthreads();

  // ---- phase 2: conv2 (32->64) with LDS-chunked weights ----
  // thread: cg=tid>>4 (co=cg*4), tg=tid&15: h=tg>>1, wp_=tg&1 ->
  // local tokens wl=2wp_, 2wp_+1 (adjacent in w): h1 cols 4wp_..4wp_+4.
  const int cg = tid >> 4, tg = tid & 15;
  const int th = tg >> 1, wp_ = tg & 1;
  float a0[4] = {0.f,0.f,0.f,0.f}, a1[4] = {0.f,0.f,0.f,0.f};
  {
    const float4* wt2g4 = (const float4*)wt2g;
    float4* w2s4 = (float4*)w2s;
    const float* hbase = &h1[(2*th)*12 + (wp_ << 2)];
    for (int c = 0; c < 4; ++c) {
      __syncthreads();
#pragma unroll
      for (int j = 0; j < 5; ++j) {
        int idx = tid + (j << 8);
        if (idx < 1152) w2s4[idx] = wt2g4[c*1152 + idx];
      }
      __syncthreads();
      const float* hb0 = hbase + (c*8)*204;
#pragma unroll 2
      for (int cil = 0; cil < 8; ++cil) {
        const float* hb = hb0 + cil*204;
        float4 A0 = *(const float4*)hb;        float s0 = hb[4];
        float4 A1 = *(const float4*)(hb + 12); float s1 = hb[16];
        float4 A2 = *(const float4*)(hb + 24); float s2 = hb[28];
        float v0[5] = {A0.x, A0.y, A0.z, A0.w, s0};
        float v1[5] = {A1.x, A1.y, A1.z, A1.w, s1};
        float v2[5] = {A2.x, A2.y, A2.z, A2.w, s2};
        const float4* wrow = (const float4*)w2s + cil*144 + cg;
#pragma unroll
        for (int kh = 0; kh < 3; ++kh) {
          const float* vr = (kh == 0) ? v0 : (kh == 1) ? v1 : v2;
#pragma unroll
          for (int kw = 0; kw < 3; ++kw) {
            float4 wq = wrow[(kh*3 + kw)*16];
            float t0 = vr[kw], t1 = vr[kw + 2];
            a0[0] += t0*wq.x; a0[1] += t0*wq.y; a0[2] += t0*wq.z; a0[3] += t0*wq.w;
            a1[0] += t1*wq.x; a1[1] += t1*wq.y; a1[2] += t1*wq.z; a1[3] += t1*wq.w;
          }
        }
      }
    }
  }
  // xe writes (xt region free since conv1 done)
  {
    const float4 bq = *(const float4*)&b2v[cg*4];
    float bias[4] = {bq.x, bq.y, bq.z, bq.w};
    const int tl0 = (2*wp_)*8 + th, tl1 = (2*wp_ + 1)*8 + th;
#pragma unroll
    for (int q = 0; q < 4; ++q) {
      int d = cg*4 + q;
      xe[tl0*68 + ((d + tl0) & 63)] = a0[q] + bias[q];
      xe[tl1*68 + ((d + tl1) & 63)] = a1[q] + bias[q];
    }
  }
  __syncthreads();

  // ---- phase 3: stage emb natural [64][68] over w2s region ----
  for (int i = tid; i < 4096; i += 256) {
    int k = i >> 6, d = i & 63;
    enat[k*68 + d] = emb[i];
  }
  __syncthreads();

  // ---- phase 4: VQ argmin, 8 lanes per token (32 local tokens) ----
  {
    const int tl = tid >> 3, dq = tid & 7;
    float xq[8];
#pragma unroll
    for (int i = 0; i < 8; i++)
      xq[i] = xe[tl*68 + ((dq*8 + i + tl) & 63)];
    float best = 3.4e38f; int bestk = 0;
    for (int k = 0; k < 64; k++) {
      const float4* ep = (const float4*)&enat[k*68 + dq*8];
      float4 e0 = ep[0], e1 = ep[1];
      float dot = e0.x*xq[0] + e0.y*xq[1] + e0.z*xq[2] + e0.w*xq[3]
                + e1.x*xq[4] + e1.y*xq[5] + e1.z*xq[6] + e1.w*xq[7];
      dot += __shfl_xor(dot, 1);
      dot += __shfl_xor(dot, 2);
      dot += __shfl_xor(dot, 4);
      float sc = norms[k] - 2.f*dot;
      if (sc < best) { best = sc; bestk = k; }
    }
    const float4* ep = (const float4*)&enat[bestk*68 + dq*8];
    float4 e0 = ep[0], e1 = ep[1];
    float d0 = e0.x-xq[0], d1 = e0.y-xq[1], d2_ = e0.z-xq[2], d3 = e0.w-xq[3];
    float d4 = e1.x-xq[4], d5 = e1.y-xq[5], d6 = e1.z-xq[6], d7 = e1.w-xq[7];
    float dd = d0*d0 + d1*d1 + d2_*d2_ + d3*d3 + d4*d4 + d5*d5 + d6*d6 + d7*d7;
    dd += __shfl_xor(dd, 1);
    dd += __shfl_xor(dd, 2);
    dd += __shfl_xor(dd, 4);
    float val = 0.f;
    if (dq == 0) {
      tokens[b*64 + (4*half + (tl >> 3))*8 + (tl & 7)] = (unsigned char)bestk;
      val = sqrtf(fmaxf(dd, 0.f));
    }
#pragma unroll
    for (int off = 1; off < 64; off <<= 1) val += __shfl_xor(val, off);
    if ((tid & 63) == 0) red[tid >> 6] = val;
    __syncthreads();
    if (tid == 0) atomicAdd(loss, (red[0]+red[1]+red[2]+red[3]) * (1.1f/4096.f));
  }
}

// ---------------------------------------------------------------------------
// k45: per image: table-gather convT1 (+bias+ReLU, bf16 dl) -> convT2 fused
// with recon loss. grid 4096 x 256.
// ---------------------------------------------------------------------------
__global__ __launch_bounds__(256) void k45(
    const float* __restrict__ x,
    const float* __restrict__ bd1v, const float* __restrict__ bd2v,
    const float* __restrict__ ws,
    const unsigned char* __restrict__ tokens,
    float* __restrict__ loss)
{
  __shared__ __align__(16) float smem[7400];
  unsigned short* dlu = (unsigned short*)smem;   // dl bf16 [32][18][20] = 11520 ush
  float* wtd2s = smem + 5760;                    // 1536
  int*   tok_s = (int*)(smem + 7296);            // 64
  float* red   = smem + 7360;                    // 8
  float* bd1s  = smem + 7368;                    // 32

  const int tid = threadIdx.x;
  const int b = blockIdx.x;
  const float4* Tg4 = (const float4*)(ws + 18432);
  const float* wtd2g = ws + 51712;

  // phase 0: zero dl; stage wtd2, bd1, tokens
  {
    float4* s4 = (float4*)smem;
    float4 z = make_float4(0.f, 0.f, 0.f, 0.f);
    for (int i = tid; i < 1440; i += 256) s4[i] = z;
    for (int i = tid; i < 1536; i += 256) wtd2s[i] = wtd2g[i];
    if (tid < 64) tok_s[tid] = tokens[b*64 + tid];
    if (tid < 32) bd1s[tid] = bd1v[tid];
  }
  __syncthreads();

  // phase 1: convT1 via table: out[oh][ow][co] = sum of 4 T rows; +bias, ReLU
  {
    const int oh = tid >> 4, ow = tid & 15;
    const int i0 = oh >> 1, r = oh & 1;
    const int jc = ow >> 1, c = ow & 1;
    const int kh0 = r ? 2 : 1, ih0 = i0;
    const int kh1 = r ? 0 : 3, ih1 = r ? i0 + 1 : i0 - 1;
    const int kw0 = c ? 2 : 1, iw0 = jc;
    const int kw1 = c ? 0 : 3, iw1 = c ? jc + 1 : jc - 1;
    const int c00 = tok_s[iw0*8 + ih0];
    const int c01 = ((unsigned)iw1 < 8u) ? tok_s[iw1*8 + ih0] : 64;
    const int c10 = ((unsigned)ih1 < 8u) ? tok_s[iw0*8 + ih1] : 64;
    const int c11 = (((unsigned)ih1 < 8u) && ((unsigned)iw1 < 8u)) ? tok_s[iw1*8 + ih1] : 64;
    const int b00 = (c00*16 + kh0*4 + kw0)*8;   // float4 index
    const int b01 = (c01*16 + kh0*4 + kw1)*8;
    const int b10 = (c10*16 + kh1*4 + kw0)*8;
    const int b11 = (c11*16 + kh1*4 + kw1)*8;
    unsigned short* dw = dlu + (oh + 1)*20 + (ow + 1);
#pragma unroll
    for (int u = 0; u < 8; u++) {
      float4 t0 = Tg4[b00 + u], t1 = Tg4[b01 + u], t2 = Tg4[b10 + u], t3 = Tg4[b11 + u];
      float4 s;
      s.x = (t0.x + t1.x) + (t2.x + t3.x);
      s.y = (t0.y + t1.y) + (t2.y + t3.y);
      s.z = (t0.z + t1.z) + (t2.z + t3.z);
      s.w = (t0.w + t1.w) + (t2.w + t3.w);
      int co = u*4;
      float v0 = s.x + bd1s[co+0]; v0 = v0 > 0.f ? v0 : 0.f;
      float v1 = s.y + bd1s[co+1]; v1 = v1 > 0.f ? v1 : 0.f;
      float v2 = s.z + bd1s[co+2]; v2 = v2 > 0.f ? v2 : 0.f;
      float v3 = s.w + bd1s[co+3]; v3 = v3 > 0.f ? v3 : 0.f;
      dw[(co+0)*360] = (unsigned short)((__float_as_uint(v0) + 0x8000u) >> 16);
      dw[(co+1)*360] = (unsigned short)((__float_as_uint(v1) + 0x8000u) >> 16);
      dw[(co+2)*360] = (unsigned short)((__float_as_uint(v2) + 0x8000u) >> 16);
      dw[(co+3)*360] = (unsigned short)((__float_as_uint(v3) + 0x8000u) >> 16);
    }
  }
  __syncthreads();

  // phase 2: convT2 (32->3, k4 s2 p1) + recon loss
  {
    const int oh = tid >> 3;
    const int ow0 = (tid & 7) * 4;
    const int p_h = (oh + 1) & 1;
    const int ihh = (oh + 1) >> 1;
    const int iwb = ow0 >> 1;
    const unsigned* dl32 = (const unsigned*)dlu;
    const float4* wf = (const float4*)wtd2s;
    float acc[3][4];
#pragma unroll
    for (int co = 0; co < 3; co++)
#pragma unroll
      for (int u = 0; u < 4; u++) acc[co][u] = 0.f;

    for (int ci = 0; ci < 32; ci++) {
      float v[2][4];
#pragma unroll
      for (int dh = 0; dh < 2; dh++) {
        int row = ihh - dh + 1;                       // [0,17]
        int us0 = ci*360 + row*20 + iwb;              // even
        unsigned ua = dl32[us0 >> 1];
        unsigned ub = dl32[(us0 >> 1) + 1];
        v[dh][0] = __uint_as_float(ua << 16);
        v[dh][1] = __uint_as_float(ua & 0xffff0000u);
        v[dh][2] = __uint_as_float(ub << 16);
        v[dh][3] = __uint_as_float(ub & 0xffff0000u);
      }
      float wv[2][12];
      int g0 = ci*12 + p_h*3;
      *(float4*)&wv[0][0] = wf[g0];     *(float4*)&wv[0][4] = wf[g0+1]; *(float4*)&wv[0][8] = wf[g0+2];
      *(float4*)&wv[1][0] = wf[g0+6];   *(float4*)&wv[1][4] = wf[g0+7]; *(float4*)&wv[1][8] = wf[g0+8];
#pragma unroll
      for (int u = 0; u < 4; u++) {
        const int pu = (u+1) & 1;
        const int cb_ = ((u+1) >> 1) + 1;
#pragma unroll
        for (int dh = 0; dh < 2; dh++)
#pragma unroll
          for (int dw_ = 0; dw_ < 2; dw_++) {
            float vv = v[dh][cb_ - dw_];
            acc[0][u] += vv * wv[dh][(pu + 2*dw_)*3 + 0];
            acc[1][u] += vv * wv[dh][(pu + 2*dw_)*3 + 1];
            acc[2][u] += vv * wv[dh][(pu + 2*dw_)*3 + 2];
          }
      }
    }
    float lsum = 0.f;
#pragma unroll
    for (int co = 0; co < 3; co++) {
      float4 xv = *(const float4*)&x[b*3072 + co*1024 + oh*32 + ow0];
      float bias = bd2v[co];
      float e0 = xv.x - (acc[co][0]+bias);
      float e1 = xv.y - (acc[co][1]+bias);
      float e2 = xv.z - (acc[co][2]+bias);
      float e3 = xv.w - (acc[co][3]+bias);
      lsum += e0*e0 + e1*e1 + e2*e2 + e3*e3;
    }
#pragma unroll
    for (int off = 1; off < 64; off <<= 1) lsum += __shfl_xor(lsum, off);
    if ((tid & 63) == 0) red[tid >> 6] = lsum;
    __syncthreads();
    if (tid == 0) atomicAdd(loss, (red[0]+red[1]+red[2]+red[3]) * (0.5f/4096.f));
  }
}

extern "C" void kernel_launch(void* const* d_in, const int* in_sizes, int n_in,
                              void* d_out, int out_size, void* d_ws, size_t ws_size,
                              hipStream_t stream) {
  const float* x   = (const float*)d_in[0];
  const float* w1  = (const float*)d_in[1];
  const float* b1  = (const float*)d_in[2];
  const float* w2  = (const float*)d_in[3];
  const float* b2  = (const float*)d_in[4];
  const float* wd1 = (const float*)d_in[5];
  const float* bd1 = (const float*)d_in[6];
  const float* wd2 = (const float*)d_in[7];
  const float* bd2 = (const float*)d_in[8];
  const float* emb = (const float*)d_in[9];
  float* out = (float*)d_out;
  float* ws  = (float*)d_ws;
  unsigned char* tokens = (unsigned char*)d_ws + 217088;

  k_init<<<72, 256, 0, stream>>>(w1, w2, wd2, ws, out);
  k_tab<<<65, 512, 0, stream>>>(emb, wd1, ws);
  k123<<<8192, 256, 0, stream>>>(x, b1, b2, emb, ws, tokens, out);
  k45<<<4096, 256, 0, stream>>>(x, bd1, bd2, ws, tokens, out);
}

// Round 6
// 544.648 us; speedup vs baseline: 1.9105x; 1.9105x over previous
//
#include <hip/hip_runtime.h>
#include <math.h>

// ---------------------------------------------------------------------------
// VQ-VAE forward, B=4096. Scalar f32 loss in d_out[0].
//
// ws float layout:
//   wt2g @ 0      : 18432  conv2 W   [(ci*9+tap)*64 + co]
//   Tg   @ 18432  : 33280  convT1 table [code(65)][kh*4+kw][co(32)], row64=0
//   wtd2g@ 51712  : 1536   convT2 W  [(ci*16+tap)*3 + co]
//   w1tg @ 53248  : 864    conv1 W   [(ci*9+tap)*32 + co]
//   normg@ 54112  : 64     ||emb_k||^2
//   SPLIT path: xeg @ float 54272 (16.78M floats), tokens @ byte 67325952
//   FUSED path: tokens @ byte 217088
// ---------------------------------------------------------------------------

__global__ __launch_bounds__(256) void k_init(
    const float* __restrict__ w1, const float* __restrict__ w2,
    const float* __restrict__ wd2, float* __restrict__ ws,
    float* __restrict__ out)
{
  int gid = blockIdx.x * 256 + threadIdx.x;
  if (gid == 0) out[0] = 0.f;
  if (gid < 18432) {                       // w2: (64co,32ci,3,3) -> [(ci*9+tap)*64+co]
    int co = gid / 288, j = gid - co*288;
    ws[j*64 + co] = w2[gid];
  }
  if (gid < 1536) {                        // wd2: (32ci,3co,4,4) -> [(ci*16+tap)*3+co]
    int ci = gid / 48, r = gid - ci*48, co = r >> 4, k = r & 15;
    ws[51712 + (ci*16 + k)*3 + co] = wd2[gid];
  }
  if (gid < 864) {                         // w1: (32co,3ci,3,3) -> [(ci*9+tap)*32+co]
    int co = gid / 27, j = gid - co*27;
    ws[53248 + j*32 + co] = w1[gid];
  }
}

// ---------------------------------------------------------------------------
// k_tab: T[code][tap][co] = sum_ci emb[code][ci] * wd1[ci][co][tap]. Row 64 = 0.
// Block 64 also writes ||emb_k||^2. grid 65 x 512.
// ---------------------------------------------------------------------------
__global__ __launch_bounds__(512) void k_tab(
    const float* __restrict__ emb, const float* __restrict__ wd1,
    float* __restrict__ ws)
{
  float* Tg = ws + 18432;
  const int code = blockIdx.x;
  const int tid = threadIdx.x;
  if (code == 64) {
    Tg[64*512 + tid] = 0.f;
    if (tid < 64) {
      const float* e = emb + tid*64;
      float s = 0.f;
      for (int j = 0; j < 64; j++) s += e[j]*e[j];
      ws[54112 + tid] = s;
    }
    return;
  }
  __shared__ float wsh[4096];
  float acc = 0.f;
  for (int cc = 0; cc < 8; cc++) {
    for (int i = tid; i < 4096; i += 512) wsh[i] = wd1[cc*4096 + i];
    __syncthreads();
    const float* eb = emb + code*64 + cc*8;
#pragma unroll
    for (int cil = 0; cil < 8; cil++) acc += eb[cil] * wsh[cil*512 + tid];
    __syncthreads();
  }
  Tg[code*512 + (tid & 15)*32 + (tid >> 4)] = acc;
}

// ---------------------------------------------------------------------------
// k12: half-image per block (grid 8192). conv1 -> conv2 -> x_enc to global.
// Round-4 conv code, VQ phases removed -> small LDS (30.7KB), capped VGPR.
// ---------------------------------------------------------------------------
__global__ __launch_bounds__(256, 3) void k12(
    const float* __restrict__ x,
    const float* __restrict__ b1v, const float* __restrict__ b2v,
    const float* __restrict__ ws,
    float* __restrict__ xeg)
{
  __shared__ __align__(16) float smem[7616];
  float* h1 = smem;            // [32][17][10] bordered
  float* xt = smem + 5440;     // [3][34][21] flat 2142 used

  const int tid  = threadIdx.x;
  const int half = blockIdx.x & 1;
  const int b    = blockIdx.x >> 1;
  const float* w1tg = ws + 53248;
  const float* wt2g = ws;

  // phase 0: zero h1; stage x half-tile (value-or-zero)
  {
    float4* h4 = (float4*)h1;
    float4 z = make_float4(0.f, 0.f, 0.f, 0.f);
    for (int i = tid; i < 1360; i += 256) h4[i] = z;
    const int ixbase = 14*half - 1;
    const float* xb = x + b*3072;
    for (int idx = tid; idx < 2142; idx += 256) {
      int ci = idx / 714;
      int rem = idx - ci*714;
      int r = rem / 21, cc = rem - r*21;
      int xr = r - 1, xc = ixbase + cc;
      float v = 0.f;
      if (cc < 19 && (unsigned)xr < 32u && (unsigned)xc < 32u)
        v = xb[ci*1024 + xr*32 + xc];
      xt[idx] = v;
    }
  }
  __syncthreads();

  // phase 1: conv1 (3->32, k3 s2 p1) + ReLU -> h1 interior
  {
    const int cs = tid >> 6, l = tid & 63;
    float acc[3][8];
#pragma unroll
    for (int i = 0; i < 3; i++)
#pragma unroll
      for (int q = 0; q < 8; q++) acc[i][q] = 0.f;
#pragma unroll 1
    for (int ci = 0; ci < 3; ci++)
#pragma unroll
      for (int kh = 0; kh < 3; kh++)
#pragma unroll
        for (int kw = 0; kw < 3; kw++) {
          const float4 w0 = *(const float4*)&w1tg[(ci*9 + kh*3 + kw)*32 + cs*8];
          const float4 w1_ = *(const float4*)&w1tg[(ci*9 + kh*3 + kw)*32 + cs*8 + 4];
#pragma unroll
          for (int i = 0; i < 3; i++) {
            int sp = i*64 + l; int spc = sp < 144 ? sp : 143;
            int lc = spc >> 4, oh1 = spc & 15;
            float xv = xt[ci*714 + (2*oh1 + kh)*21 + (2*lc + kw)];
            acc[i][0] += w0.x*xv; acc[i][1] += w0.y*xv; acc[i][2] += w0.z*xv; acc[i][3] += w0.w*xv;
            acc[i][4] += w1_.x*xv; acc[i][5] += w1_.y*xv; acc[i][6] += w1_.z*xv; acc[i][7] += w1_.w*xv;
          }
        }
    const float4 b0 = *(const float4*)&b1v[cs*8];
    const float4 b1_ = *(const float4*)&b1v[cs*8 + 4];
    float bias[8] = {b0.x,b0.y,b0.z,b0.w,b1_.x,b1_.y,b1_.z,b1_.w};
#pragma unroll
    for (int i = 0; i < 3; i++) {
      int sp = i*64 + l;
      if (sp < 144) {
        int lc = sp >> 4, oh1 = sp & 15;
#pragma unroll
        for (int q = 0; q < 8; q++) {
          float v = acc[i][q] + bias[q];
          h1[(cs*8 + q)*170 + (oh1 + 1)*10 + (lc + 1)] = v > 0.f ? v : 0.f;
        }
      }
    }
  }
  __syncthreads();

  // phase 2: conv2 (32->64, k3 s2 p1) -> x_enc global [b][t][d]
  {
    const int cg = tid >> 4, tg = tid & 15;
    const int h0 = (2*tg) & 7;
    const int lw = tg >> 2;
    const int colb = half + 2*lw;
    float a00=0.f,a01=0.f,a02=0.f,a03=0.f, a10=0.f,a11=0.f,a12=0.f,a13=0.f;
    const float* hb = h1 + (2*h0)*10 + colb;
    for (int ci = 0; ci < 32; ci++) {
      const float* hc = hb + ci*170;
#pragma unroll
      for (int kw = 0; kw < 3; kw++) {
        float vr0 = hc[kw];
        float vr1 = hc[10 + kw];
        float vr2 = hc[20 + kw];
        float vr3 = hc[30 + kw];
        float vr4 = hc[40 + kw];
#pragma unroll
        for (int kh = 0; kh < 3; kh++) {
          const float4 wq = *(const float4*)&wt2g[((ci*9 + kh*3 + kw) << 6) + cg*4];
          float v1 = (kh == 0) ? vr0 : (kh == 1 ? vr1 : vr2);
          float v2 = (kh == 0) ? vr2 : (kh == 1 ? vr3 : vr4);
          a00 += v1*wq.x; a01 += v1*wq.y; a02 += v1*wq.z; a03 += v1*wq.w;
          a10 += v2*wq.x; a11 += v2*wq.y; a12 += v2*wq.z; a13 += v2*wq.w;
        }
      }
    }
    const float4 bq = *(const float4*)&b2v[cg*4];
    const int t0g = 32*half + 2*tg;
    float4 o0 = make_float4(a00+bq.x, a01+bq.y, a02+bq.z, a03+bq.w);
    float4 o1 = make_float4(a10+bq.x, a11+bq.y, a12+bq.z, a13+bq.w);
    *(float4*)&xeg[(b << 12) + (t0g << 6) + (cg << 2)]       = o0;
    *(float4*)&xeg[(b << 12) + ((t0g + 1) << 6) + (cg << 2)] = o1;
  }
}

// ---------------------------------------------------------------------------
// kVQ: 4 lanes x 16 dims per token-pair. grid 2048 x 256 covers 262144 tokens.
// Emits tokens + (1+beta)*sum||e-x_enc|| loss.
// ---------------------------------------------------------------------------
__global__ __launch_bounds__(256) void kVQ(
    const float* __restrict__ xeg, const float* __restrict__ emb,
    const float* __restrict__ ws,
    unsigned char* __restrict__ tokens, float* __restrict__ loss)
{
  __shared__ __align__(16) float enat[4356];
  __shared__ float norms[64];
  __shared__ float red[4];
  const int tid = threadIdx.x;
  for (int i = tid; i < 4096; i += 256) {
    int k = i >> 6, d = i & 63;
    enat[k*68 + d] = emb[i];
  }
  if (tid < 64) norms[tid] = ws[54112 + tid];
  __syncthreads();

  const int gid = blockIdx.x*256 + tid;
  const int pr = gid >> 2;
  const int dq = gid & 3;
  const int T0 = pr*2, T1 = T0 + 1;
  float xq0[16], xq1[16];
  const float4* xr0 = (const float4*)&xeg[T0*64 + dq*16];
  const float4* xr1 = (const float4*)&xeg[T1*64 + dq*16];
#pragma unroll
  for (int u = 0; u < 4; u++) {
    float4 a = xr0[u];
    xq0[u*4+0]=a.x; xq0[u*4+1]=a.y; xq0[u*4+2]=a.z; xq0[u*4+3]=a.w;
    float4 c = xr1[u];
    xq1[u*4+0]=c.x; xq1[u*4+1]=c.y; xq1[u*4+2]=c.z; xq1[u*4+3]=c.w;
  }
  float best0 = 3.4e38f, best1 = 3.4e38f;
  int k0 = 0, k1 = 0;
  for (int k = 0; k < 64; k++) {
    const float4* ep = (const float4*)&enat[k*68 + dq*16];
    float d0 = 0.f, d1 = 0.f;
#pragma unroll
    for (int u = 0; u < 4; u++) {
      float4 e = ep[u];
      d0 += e.x*xq0[u*4+0] + e.y*xq0[u*4+1] + e.z*xq0[u*4+2] + e.w*xq0[u*4+3];
      d1 += e.x*xq1[u*4+0] + e.y*xq1[u*4+1] + e.z*xq1[u*4+2] + e.w*xq1[u*4+3];
    }
    d0 += __shfl_xor(d0, 1); d0 += __shfl_xor(d0, 2);
    d1 += __shfl_xor(d1, 1); d1 += __shfl_xor(d1, 2);
    float s0 = norms[k] - 2.f*d0;
    float s1 = norms[k] - 2.f*d1;
    if (s0 < best0) { best0 = s0; k0 = k; }
    if (s1 < best1) { best1 = s1; k1 = k; }
  }
  float v01 = 0.f;
  {
    const float4* ep = (const float4*)&enat[k0*68 + dq*16];
    float dd0 = 0.f;
#pragma unroll
    for (int u = 0; u < 4; u++) {
      float4 e = ep[u];
      float t0 = e.x - xq0[u*4+0], t1 = e.y - xq0[u*4+1];
      float t2 = e.z - xq0[u*4+2], t3 = e.w - xq0[u*4+3];
      dd0 += t0*t0 + t1*t1 + t2*t2 + t3*t3;
    }
    const float4* eq = (const float4*)&enat[k1*68 + dq*16];
    float dd1 = 0.f;
#pragma unroll
    for (int u = 0; u < 4; u++) {
      float4 e = eq[u];
      float t0 = e.x - xq1[u*4+0], t1 = e.y - xq1[u*4+1];
      float t2 = e.z - xq1[u*4+2], t3 = e.w - xq1[u*4+3];
      dd1 += t0*t0 + t1*t1 + t2*t2 + t3*t3;
    }
    dd0 += __shfl_xor(dd0, 1); dd0 += __shfl_xor(dd0, 2);
    dd1 += __shfl_xor(dd1, 1); dd1 += __shfl_xor(dd1, 2);
    if (dq == 0) {
      tokens[T0] = (unsigned char)k0;
      tokens[T1] = (unsigned char)k1;
      v01 = sqrtf(fmaxf(dd0, 0.f)) + sqrtf(fmaxf(dd1, 0.f));
    }
  }
#pragma unroll
  for (int off = 1; off < 64; off <<= 1) v01 += __shfl_xor(v01, off);
  if ((tid & 63) == 0) red[tid >> 6] = v01;
  __syncthreads();
  if (tid == 0) atomicAdd(loss, (red[0]+red[1]+red[2]+red[3]) * (1.1f/4096.f));
}

// ---------------------------------------------------------------------------
// k123_fused: EXACT round-4 kernel — fallback when ws_size too small.
// ---------------------------------------------------------------------------
__global__ __launch_bounds__(256) void k123_fused(
    const float* __restrict__ x,
    const float* __restrict__ b1v, const float* __restrict__ b2v,
    const float* __restrict__ emb,
    const float* __restrict__ ws,
    unsigned char* __restrict__ tokens,
    float* __restrict__ loss)
{
  __shared__ __align__(16) float smem[7688];
  float* h1   = smem;
  float* enat = smem;
  float* xt   = smem + 5440;
  float* xe   = smem + 5440;
  float* norms = smem + 7616;
  float* red  = smem + 7680;

  const int tid  = threadIdx.x;
  const int half = blockIdx.x & 1;
  const int b    = blockIdx.x >> 1;
  const float* w1tg = ws + 53248;
  const float* wt2g = ws;

  {
    float4* s4 = (float4*)smem;
    float4 z = make_float4(0.f, 0.f, 0.f, 0.f);
    for (int i = tid; i < 1922; i += 256) s4[i] = z;
  }
  __syncthreads();
  {
    const int ixbase = 14*half - 1;
    const float* xb = x + b*3072;
    for (int idx = tid; idx < 2142; idx += 256) {
      int ci = idx / 714;
      int rem = idx - ci*714;
      int r = rem / 21, cc = rem - r*21;
      int xr = r - 1, xc = ixbase + cc;
      if (cc < 19 && (unsigned)xr < 32u && (unsigned)xc < 32u)
        xt[idx] = xb[ci*1024 + xr*32 + xc];
    }
  }
  __syncthreads();
  {
    const int cs = tid >> 6, l = tid & 63;
    float acc[3][8];
#pragma unroll
    for (int i = 0; i < 3; i++)
#pragma unroll
      for (int q = 0; q < 8; q++) acc[i][q] = 0.f;
#pragma unroll
    for (int ci = 0; ci < 3; ci++)
#pragma unroll
      for (int kh = 0; kh < 3; kh++)
#pragma unroll
        for (int kw = 0; kw < 3; kw++) {
          const float4 w0 = *(const float4*)&w1tg[(ci*9 + kh*3 + kw)*32 + cs*8];
          const float4 w1_ = *(const float4*)&w1tg[(ci*9 + kh*3 + kw)*32 + cs*8 + 4];
#pragma unroll
          for (int i = 0; i < 3; i++) {
            int sp = i*64 + l; int spc = sp < 144 ? sp : 143;
            int lc = spc >> 4, oh1 = spc & 15;
            float xv = xt[ci*714 + (2*oh1 + kh)*21 + (2*lc + kw)];
            acc[i][0] += w0.x*xv; acc[i][1] += w0.y*xv; acc[i][2] += w0.z*xv; acc[i][3] += w0.w*xv;
            acc[i][4] += w1_.x*xv; acc[i][5] += w1_.y*xv; acc[i][6] += w1_.z*xv; acc[i][7] += w1_.w*xv;
          }
        }
    const float4 b0 = *(const float4*)&b1v[cs*8];
    const float4 b1_ = *(const float4*)&b1v[cs*8 + 4];
    float bias[8] = {b0.x,b0.y,b0.z,b0.w,b1_.x,b1_.y,b1_.z,b1_.w};
#pragma unroll
    for (int i = 0; i < 3; i++) {
      int sp = i*64 + l;
      if (sp < 144) {
        int lc = sp >> 4, oh1 = sp & 15;
#pragma unroll
        for (int q = 0; q < 8; q++) {
          float v = acc[i][q] + bias[q];
          h1[(cs*8 + q)*170 + (oh1 + 1)*10 + (lc + 1)] = v > 0.f ? v : 0.f;
        }
      }
    }
  }
  __syncthreads();
  {
    const int cg = tid >> 4, tg = tid & 15;
    const int h0 = (2*tg) & 7;
    const int lw = tg >> 2;
    const int colb = half + 2*lw;
    float a00=0.f,a01=0.f,a02=0.f,a03=0.f, a10=0.f,a11=0.f,a12=0.f,a13=0.f;
    const float* hb = h1 + (2*h0)*10 + colb;
    for (int ci = 0; ci < 32; ci++) {
      const float* hc = hb + ci*170;
#pragma unroll
      for (int kw = 0; kw < 3; kw++) {
        float vr0 = hc[kw];
        float vr1 = hc[10 + kw];
        float vr2 = hc[20 + kw];
        float vr3 = hc[30 + kw];
        float vr4 = hc[40 + kw];
#pragma unroll
        for (int kh = 0; kh < 3; kh++) {
          const float4 wq = *(const float4*)&wt2g[((ci*9 + kh*3 + kw) << 6) + cg*4];
          float v1 = (kh == 0) ? vr0 : (kh == 1 ? vr1 : vr2);
          float v2 = (kh == 0) ? vr2 : (kh == 1 ? vr3 : vr4);
          a00 += v1*wq.x; a01 += v1*wq.y; a02 += v1*wq.z; a03 += v1*wq.w;
          a10 += v2*wq.x; a11 += v2*wq.y; a12 += v2*wq.z; a13 += v2*wq.w;
        }
      }
    }
    const float4 bq = *(const float4*)&b2v[cg*4];
    {
      int t = 2*tg;
      xe[t*68 + ((cg*4 + 0 + t) & 63)] = a00 + bq.x;
      xe[t*68 + ((cg*4 + 1 + t) & 63)] = a01 + bq.y;
      xe[t*68 + ((cg*4 + 2 + t) & 63)] = a02 + bq.z;
      xe[t*68 + ((cg*4 + 3 + t) & 63)] = a03 + bq.w;
      t = 2*tg + 1;
      xe[t*68 + ((cg*4 + 0 + t) & 63)] = a10 + bq.x;
      xe[t*68 + ((cg*4 + 1 + t) & 63)] = a11 + bq.y;
      xe[t*68 + ((cg*4 + 2 + t) & 63)] = a12 + bq.z;
      xe[t*68 + ((cg*4 + 3 + t) & 63)] = a13 + bq.w;
    }
  }
  __syncthreads();
  for (int i = tid; i < 4096; i += 256) {
    int k = i >> 6, d = i & 63;
    enat[k*68 + d] = emb[i];
  }
  if (tid < 64) norms[tid] = ws[54112 + tid];
  __syncthreads();
  {
    const int tl = tid >> 3, dq = tid & 7;
    float xq[8];
#pragma unroll
    for (int i = 0; i < 8; i++)
      xq[i] = xe[tl*68 + ((dq*8 + i + tl) & 63)];
    float best = 3.4e38f; int bestk = 0;
    for (int k = 0; k < 64; k++) {
      const float4* ep = (const float4*)&enat[k*68 + dq*8];
      float4 e0 = ep[0], e1 = ep[1];
      float dot = e0.x*xq[0] + e0.y*xq[1] + e0.z*xq[2] + e0.w*xq[3]
                + e1.x*xq[4] + e1.y*xq[5] + e1.z*xq[6] + e1.w*xq[7];
      dot += __shfl_xor(dot, 1);
      dot += __shfl_xor(dot, 2);
      dot += __shfl_xor(dot, 4);
      float sc = norms[k] - 2.f*dot;
      if (sc < best) { best = sc; bestk = k; }
    }
    const float4* ep = (const float4*)&enat[bestk*68 + dq*8];
    float4 e0 = ep[0], e1 = ep[1];
    float d0 = e0.x-xq[0], d1 = e0.y-xq[1], d2_ = e0.z-xq[2], d3 = e0.w-xq[3];
    float d4 = e1.x-xq[4], d5 = e1.y-xq[5], d6 = e1.z-xq[6], d7 = e1.w-xq[7];
    float dd = d0*d0 + d1*d1 + d2_*d2_ + d3*d3 + d4*d4 + d5*d5 + d6*d6 + d7*d7;
    dd += __shfl_xor(dd, 1);
    dd += __shfl_xor(dd, 2);
    dd += __shfl_xor(dd, 4);
    float val = 0.f;
    if (dq == 0) {
      tokens[b*64 + (4*half + (tl >> 3))*8 + (tl & 7)] = (unsigned char)bestk;
      val = sqrtf(fmaxf(dd, 0.f));
    }
#pragma unroll
    for (int off = 1; off < 64; off <<= 1) val += __shfl_xor(val, off);
    if ((tid & 63) == 0) red[tid >> 6] = val;
    __syncthreads();
    if (tid == 0) atomicAdd(loss, (red[0]+red[1]+red[2]+red[3]) * (1.1f/4096.f));
  }
}

// ---------------------------------------------------------------------------
// k45: per image: table-gather convT1 (+bias+ReLU, bf16 dl) -> convT2 fused
// with recon loss. grid 4096 x 256.
// ---------------------------------------------------------------------------
__global__ __launch_bounds__(256) void k45(
    const float* __restrict__ x,
    const float* __restrict__ bd1v, const float* __restrict__ bd2v,
    const float* __restrict__ ws,
    const unsigned char* __restrict__ tokens,
    float* __restrict__ loss)
{
  __shared__ __align__(16) float smem[7400];
  unsigned short* dlu = (unsigned short*)smem;   // dl bf16 [32][18][20]
  float* wtd2s = smem + 5760;
  int*   tok_s = (int*)(smem + 7296);
  float* red   = smem + 7360;
  float* bd1s  = smem + 7368;

  const int tid = threadIdx.x;
  const int b = blockIdx.x;
  const float4* Tg4 = (const float4*)(ws + 18432);
  const float* wtd2g = ws + 51712;

  {
    float4* s4 = (float4*)smem;
    float4 z = make_float4(0.f, 0.f, 0.f, 0.f);
    for (int i = tid; i < 1440; i += 256) s4[i] = z;
    for (int i = tid; i < 1536; i += 256) wtd2s[i] = wtd2g[i];
    if (tid < 64) tok_s[tid] = tokens[b*64 + tid];
    if (tid < 32) bd1s[tid] = bd1v[tid];
  }
  __syncthreads();

  {
    const int oh = tid >> 4, ow = tid & 15;
    const int i0 = oh >> 1, r = oh & 1;
    const int jc = ow >> 1, c = ow & 1;
    const int kh0 = r ? 2 : 1, ih0 = i0;
    const int kh1 = r ? 0 : 3, ih1 = r ? i0 + 1 : i0 - 1;
    const int kw0 = c ? 2 : 1, iw0 = jc;
    const int kw1 = c ? 0 : 3, iw1 = c ? jc + 1 : jc - 1;
    const int c00 = tok_s[iw0*8 + ih0];
    const int c01 = ((unsigned)iw1 < 8u) ? tok_s[iw1*8 + ih0] : 64;
    const int c10 = ((unsigned)ih1 < 8u) ? tok_s[iw0*8 + ih1] : 64;
    const int c11 = (((unsigned)ih1 < 8u) && ((unsigned)iw1 < 8u)) ? tok_s[iw1*8 + ih1] : 64;
    const int b00 = (c00*16 + kh0*4 + kw0)*8;
    const int b01 = (c01*16 + kh0*4 + kw1)*8;
    const int b10 = (c10*16 + kh1*4 + kw0)*8;
    const int b11 = (c11*16 + kh1*4 + kw1)*8;
    unsigned short* dw = dlu + (oh + 1)*20 + (ow + 1);
#pragma unroll
    for (int u = 0; u < 8; u++) {
      float4 t0 = Tg4[b00 + u], t1 = Tg4[b01 + u], t2 = Tg4[b10 + u], t3 = Tg4[b11 + u];
      float4 s;
      s.x = (t0.x + t1.x) + (t2.x + t3.x);
      s.y = (t0.y + t1.y) + (t2.y + t3.y);
      s.z = (t0.z + t1.z) + (t2.z + t3.z);
      s.w = (t0.w + t1.w) + (t2.w + t3.w);
      int co = u*4;
      float v0 = s.x + bd1s[co+0]; v0 = v0 > 0.f ? v0 : 0.f;
      float v1 = s.y + bd1s[co+1]; v1 = v1 > 0.f ? v1 : 0.f;
      float v2 = s.z + bd1s[co+2]; v2 = v2 > 0.f ? v2 : 0.f;
      float v3 = s.w + bd1s[co+3]; v3 = v3 > 0.f ? v3 : 0.f;
      dw[(co+0)*360] = (unsigned short)((__float_as_uint(v0) + 0x8000u) >> 16);
      dw[(co+1)*360] = (unsigned short)((__float_as_uint(v1) + 0x8000u) >> 16);
      dw[(co+2)*360] = (unsigned short)((__float_as_uint(v2) + 0x8000u) >> 16);
      dw[(co+3)*360] = (unsigned short)((__float_as_uint(v3) + 0x8000u) >> 16);
    }
  }
  __syncthreads();

  {
    const int oh = tid >> 3;
    const int ow0 = (tid & 7) * 4;
    const int p_h = (oh + 1) & 1;
    const int ihh = (oh + 1) >> 1;
    const int iwb = ow0 >> 1;
    const unsigned* dl32 = (const unsigned*)dlu;
    const float4* wf = (const float4*)wtd2s;
    float acc[3][4];
#pragma unroll
    for (int co = 0; co < 3; co++)
#pragma unroll
      for (int u = 0; u < 4; u++) acc[co][u] = 0.f;

    for (int ci = 0; ci < 32; ci++) {
      float v[2][4];
#pragma unroll
      for (int dh = 0; dh < 2; dh++) {
        int row = ihh - dh + 1;
        int us0 = ci*360 + row*20 + iwb;
        unsigned ua = dl32[us0 >> 1];
        unsigned ub = dl32[(us0 >> 1) + 1];
        v[dh][0] = __uint_as_float(ua << 16);
        v[dh][1] = __uint_as_float(ua & 0xffff0000u);
        v[dh][2] = __uint_as_float(ub << 16);
        v[dh][3] = __uint_as_float(ub & 0xffff0000u);
      }
      float wv[2][12];
      int g0 = ci*12 + p_h*3;
      *(float4*)&wv[0][0] = wf[g0];     *(float4*)&wv[0][4] = wf[g0+1]; *(float4*)&wv[0][8] = wf[g0+2];
      *(float4*)&wv[1][0] = wf[g0+6];   *(float4*)&wv[1][4] = wf[g0+7]; *(float4*)&wv[1][8] = wf[g0+8];
#pragma unroll
      for (int u = 0; u < 4; u++) {
        const int pu = (u+1) & 1;
        const int cb_ = ((u+1) >> 1) + 1;
#pragma unroll
        for (int dh = 0; dh < 2; dh++)
#pragma unroll
          for (int dw_ = 0; dw_ < 2; dw_++) {
            float vv = v[dh][cb_ - dw_];
            acc[0][u] += vv * wv[dh][(pu + 2*dw_)*3 + 0];
            acc[1][u] += vv * wv[dh][(pu + 2*dw_)*3 + 1];
            acc[2][u] += vv * wv[dh][(pu + 2*dw_)*3 + 2];
          }
      }
    }
    float lsum = 0.f;
#pragma unroll
    for (int co = 0; co < 3; co++) {
      float4 xv = *(const float4*)&x[b*3072 + co*1024 + oh*32 + ow0];
      float bias = bd2v[co];
      float e0 = xv.x - (acc[co][0]+bias);
      float e1 = xv.y - (acc[co][1]+bias);
      float e2 = xv.z - (acc[co][2]+bias);
      float e3 = xv.w - (acc[co][3]+bias);
      lsum += e0*e0 + e1*e1 + e2*e2 + e3*e3;
    }
#pragma unroll
    for (int off = 1; off < 64; off <<= 1) lsum += __shfl_xor(lsum, off);
    if ((tid & 63) == 0) red[tid >> 6] = lsum;
    __syncthreads();
    if (tid == 0) atomicAdd(loss, (red[0]+red[1]+red[2]+red[3]) * (0.5f/4096.f));
  }
}

extern "C" void kernel_launch(void* const* d_in, const int* in_sizes, int n_in,
                              void* d_out, int out_size, void* d_ws, size_t ws_size,
                              hipStream_t stream) {
  const float* x   = (const float*)d_in[0];
  const float* w1  = (const float*)d_in[1];
  const float* b1  = (const float*)d_in[2];
  const float* w2  = (const float*)d_in[3];
  const float* b2  = (const float*)d_in[4];
  const float* wd1 = (const float*)d_in[5];
  const float* bd1 = (const float*)d_in[6];
  const float* wd2 = (const float*)d_in[7];
  const float* bd2 = (const float*)d_in[8];
  const float* emb = (const float*)d_in[9];
  float* out = (float*)d_out;
  float* ws  = (float*)d_ws;

  k_init<<<72, 256, 0, stream>>>(w1, w2, wd2, ws, out);
  k_tab<<<65, 512, 0, stream>>>(emb, wd1, ws);

  const size_t NEED = 67588096ULL;  // xeg (64MB @ float 54272) + tokens
  if (ws_size >= NEED) {
    float* xeg = ws + 54272;
    unsigned char* tokens = (unsigned char*)d_ws + 67325952;
    k12<<<8192, 256, 0, stream>>>(x, b1, b2, ws, xeg);
    kVQ<<<2048, 256, 0, stream>>>(xeg, emb, ws, tokens, out);
    k45<<<4096, 256, 0, stream>>>(x, bd1, bd2, ws, tokens, out);
  } else {
    unsigned char* tokens = (unsigned char*)d_ws + 217088;
    k123_fused<<<8192, 256, 0, stream>>>(x, b1, b2, emb, ws, tokens, out);
    k45<<<4096, 256, 0, stream>>>(x, bd1, bd2, ws, tokens, out);
  }
}